// Round 9
// baseline (2642.628 us; speedup 1.0000x reference)
//
#include <hip/hip_runtime.h>
#include <hip/hip_bf16.h>

#define NH 4
#define DH 256
#define DMODEL 1024
#define BB 4
#define SS 2048

typedef __attribute__((ext_vector_type(4))) float f32x4;
typedef __attribute__((ext_vector_type(8))) short bf16x8;
typedef __attribute__((ext_vector_type(4))) int i32x4;

__device__ __forceinline__ int dot4i8(int acc, int a, int b) {
#if __has_builtin(__builtin_amdgcn_sdot4)
    return __builtin_amdgcn_sdot4(a, b, acc, false);
#else
#pragma unroll
    for (int i = 0; i < 4; ++i) {
        int av = (a << (24 - 8 * i)) >> 24;
        int bv = (b << (24 - 8 * i)) >> 24;
        acc += av * bv;
    }
    return acc;
#endif
}

// Raw workgroup barrier: orders LDS only; global loads/stores stay in flight.
__device__ __forceinline__ void wg_barrier() {
    asm volatile("s_waitcnt lgkmcnt(0)" ::: "memory");
    __builtin_amdgcn_s_barrier();
    __builtin_amdgcn_sched_barrier(0);
}

// ---------------- conv + swish ----------------
__global__ void k_conv(const float* __restrict__ x, const float* __restrict__ cw,
                       const float* __restrict__ cb, float* __restrict__ xc) {
    int bs = blockIdx.x;              // b*2048 + s
    int s = bs & (SS - 1);
    const float* xrow = x + (size_t)bs * DMODEL;
#pragma unroll
    for (int dd = 0; dd < 4; ++dd) {
        int d = threadIdx.x + dd * 256;
        float w0 = cw[d * 4 + 0], w1 = cw[d * 4 + 1], w2 = cw[d * 4 + 2], w3 = cw[d * 4 + 3];
        float acc = cb[d] + w3 * xrow[d];
        if (s >= 1) acc += w2 * xrow[d - DMODEL];
        if (s >= 2) acc += w1 * xrow[d - 2 * DMODEL];
        if (s >= 3) acc += w0 * xrow[d - 3 * DMODEL];
        float sig = 1.f / (1.f + __expf(-acc));
        xc[(size_t)bs * DMODEL + d] = acc * sig;
    }
}

// ---------------- headwise projections (bf16 MFMA GEMM) ----------------
// gates layout: [b][h][s][g][d]
__global__ void k_gemm(const float* __restrict__ x, const float* __restrict__ xc,
                       const float* __restrict__ wi, const float* __restrict__ wf,
                       const float* __restrict__ wz, const float* __restrict__ wo,
                       float* __restrict__ gates) {
    int h = blockIdx.z >> 1, pair = blockIdx.z & 1;
    const float* A = pair ? x : xc;
    int n0 = blockIdx.y * 64;  // in [0,512)
    const float* W = (n0 < 256) ? (pair ? wz : wi) : (pair ? wo : wf);
    int nl = n0 & 255;
    int m0 = blockIdx.x * 64;

    __shared__ __align__(16) __hip_bfloat16 Al[64][72];
    __shared__ __align__(16) __hip_bfloat16 Bl[64][72];

    int tid = threadIdx.x;
    int lane = tid & 63, wv = tid >> 6;
    f32x4 acc[4] = {};

    for (int k0 = 0; k0 < 256; k0 += 64) {
        __syncthreads();
#pragma unroll
        for (int i = 0; i < 4; ++i) {
            int f4 = tid + i * 256;
            int r = f4 >> 4, c4 = (f4 & 15) * 4;
            const float* srcA = A + (size_t)(m0 + r) * DMODEL + h * DH + k0 + c4;
            float4 v = *(const float4*)srcA;
            Al[r][c4 + 0] = __float2bfloat16(v.x);
            Al[r][c4 + 1] = __float2bfloat16(v.y);
            Al[r][c4 + 2] = __float2bfloat16(v.z);
            Al[r][c4 + 3] = __float2bfloat16(v.w);
            const float* srcB = W + (size_t)(h * DH + nl + r) * DH + k0 + c4;
            float4 u = *(const float4*)srcB;
            Bl[r][c4 + 0] = __float2bfloat16(u.x);
            Bl[r][c4 + 1] = __float2bfloat16(u.y);
            Bl[r][c4 + 2] = __float2bfloat16(u.z);
            Bl[r][c4 + 3] = __float2bfloat16(u.w);
        }
        __syncthreads();
#pragma unroll
        for (int kk = 0; kk < 64; kk += 32) {
            bf16x8 a = *(const bf16x8*)&Al[wv * 16 + (lane & 15)][kk + (lane >> 4) * 8];
#pragma unroll
            for (int nt = 0; nt < 4; ++nt) {
                bf16x8 bfr = *(const bf16x8*)&Bl[nt * 16 + (lane & 15)][kk + (lane >> 4) * 8];
                acc[nt] = __builtin_amdgcn_mfma_f32_16x16x32_bf16(a, bfr, acc[nt], 0, 0, 0);
            }
        }
    }
#pragma unroll
    for (int nt = 0; nt < 4; ++nt)
#pragma unroll
        for (int r = 0; r < 4; ++r) {
            int m = m0 + wv * 16 + (lane >> 4) * 4 + r;
            int n = n0 + nt * 16 + (lane & 15);
            int b = m >> 11, s = m & (SS - 1);
            int g = pair * 2 + (n >> 8), d = n & 255;
            gates[((((size_t)(b * NH + h)) * SS + s) * 4 + g) * DH + d] = acc[nt][r];
        }
}

// ---------------- weight prep: per-column int8 quantization of R ----------------
// Wq[(h*64 + j)*1024 + col]: 4 i8 packed (byte i = R[h][4j+i][col] quantized)
__global__ void k_prep(const float* __restrict__ R, int* __restrict__ Wq,
                       float* __restrict__ scales) {
    int colid = blockIdx.x * 4 + (threadIdx.x >> 6);  // 0..4095
    int lane = threadIdx.x & 63;
    int h = colid >> 10, k = colid & 1023;
    const float* base = R + (size_t)h * 256 * 1024 + k;
    float v[4];
    float mx = 0.f;
#pragma unroll
    for (int i = 0; i < 4; ++i) {
        v[i] = base[(size_t)(lane * 4 + i) * 1024];
        mx = fmaxf(mx, fabsf(v[i]));
    }
    for (int off = 32; off; off >>= 1) mx = fmaxf(mx, __shfl_xor(mx, off));
    mx = fmaxf(mx, 1e-30f);
    float scale = mx * (1.f / 127.f);
    float inv = 127.f / mx;
    int pk = 0;
#pragma unroll
    for (int i = 0; i < 4; ++i) {
        int q = (int)rintf(v[i] * inv);
        q = max(-127, min(127, q));
        pk |= (q & 255) << (8 * i);
    }
    Wq[(h * 64 + lane) * 1024 + k] = pk;
    if (lane == 0) scales[h * 1024 + k] = scale;
}

// ---------------- the sequential sLSTM scan (two-pipe, round-6 structure) ----------------
// Round 6 with ONE change: the readlane-SGPR dot phase (measured ~2164 VALU
// cyc/SIMD/step of serialization) is replaced by round-3's LDS-broadcast dots
// (16 wave-uniform ds_read_b128 of hq; dots consume i32x4 components from
// VGPRs; 4 independent accumulators -- integer adds, bit-exact any order).
// Partition (verified correct in round 6, absmax 0.0625):
//   wave wv owns d in [32wv, 32wv+32) for ALL FOUR gates.
//   * i,f via mfma_i32_16x16x64_i8, 4 tiles x 4 K-chunks = 16 MFMA/wave;
//     B-fragments MFMA-consumable -> RA may AGPR them at zero cost.
//   * z,o via v_dot4: lane l<32 owns z[32wv+l], l>=32 owns o[32wv+l-32];
//     w[64] dwords/lane -- the footprint round 6 PROVED arch-resident
//     (VGPR_Count=100 = 64 w + ~36 live).
// Cell in-wave: i,f from own MFMA accs via __shfl(cl), o via __shfl(l|32).
// No rec[] LDS, ONE barrier/step, hq double-buffered, distance-2 gate
// prefetch rides across the raw barrier.
__launch_bounds__(512, 2)
__global__ void k_scan(const float* __restrict__ gates, const int* __restrict__ Wq,
                       const float* __restrict__ scales, const float* __restrict__ bias,
                       float* __restrict__ y) {
    int bh = blockIdx.x;
    int h = bh & 3;
    int t = threadIdx.x;
    int l = t & 63;          // lane
    int wv = t >> 6;         // wave 0..7
    int kg = l >> 4;         // K-group within MFMA fragment
    int cl = l & 15;
    int lz = l & 31;
    int d = wv * 32 + lz;    // this lane's cell index (lanes 0..31 own it)

    __shared__ __align__(16) signed char hq[2][256];

    // ---- MFMA B-fragments: tiles ti = g*2+tt, g in {i=0,f=1}, tt in {0,1}
    i32x4 bfr[4][4];
#pragma unroll
    for (int ti = 0; ti < 4; ++ti) {
        int g = ti >> 1, tt = ti & 1;
        int col = g * 256 + wv * 32 + tt * 16 + cl;
#pragma unroll
        for (int c = 0; c < 4; ++c)
#pragma unroll
            for (int j4 = 0; j4 < 4; ++j4)
                bfr[ti][c][j4] = Wq[(h * 64 + c * 16 + kg * 4 + j4) * 1024 + col];
    }
    i32x4 acc[4];
#pragma unroll
    for (int ti = 0; ti < 4; ++ti) acc[ti] = (i32x4){0, 0, 0, 0};

    // ---- dot4 weights: this lane's z- or o-column (64 dwords, arch-resident)
    int dotcol = (l < 32) ? (512 + wv * 32 + l) : (768 + wv * 32 + (l - 32));
    int w[64];
#pragma unroll
    for (int j = 0; j < 64; ++j) w[j] = Wq[(h * 64 + j) * 1024 + dotcol];

    float cmi = scales[h * 1024 + d] * (1.f / 127.f);
    float cmf = scales[h * 1024 + 256 + d] * (1.f / 127.f);
    float cmz = scales[h * 1024 + 512 + d] * (1.f / 127.f);
    float cmo = scales[h * 1024 + 768 + d] * (1.f / 127.f);
    float bi = bias[(0 * NH + h) * DH + d];
    float bf_ = bias[(1 * NH + h) * DH + d];
    float bz = bias[(2 * NH + h) * DH + d];
    float bo = bias[(3 * NH + h) * DH + d];

    float c_ = 0.f, n_ = 0.f, mstate = 0.f;
    const float* gbase = gates + (size_t)bh * SS * 1024;
    float* ybase = y + (size_t)bh * SS * DH;

    if (t < 32) ((i32x4*)hq)[t] = (i32x4){0, 0, 0, 0};
    __syncthreads();

    // gate ping-pong (distance-2 prefetch; only cell lanes load)
    float gA0 = 0, gA1 = 0, gA2 = 0, gA3 = 0, gB0 = 0, gB1 = 0, gB2 = 0, gB3 = 0;
    if (l < 32) {
        gA0 = gbase[d]; gA1 = gbase[256 + d]; gA2 = gbase[512 + d]; gA3 = gbase[768 + d];
        gB0 = gbase[1024 + d]; gB1 = gbase[1024 + 256 + d];
        gB2 = gbase[1024 + 512 + d]; gB3 = gbase[1024 + 768 + d];
    }

#define SCAN_STEP(P, G0, G1, G2, G3, SCUR)                                     \
    {                                                                          \
        float p0 = 0, p1 = 0, p2 = 0, p3 = 0;                                  \
        if (l < 32) {                                                          \
            int sp = (SCUR) + 2 < SS ? (SCUR) + 2 : SS - 1;                    \
            const float* gp = gbase + (size_t)sp * 1024 + d;                   \
            p0 = gp[0]; p1 = gp[256]; p2 = gp[512]; p3 = gp[768];              \
        }                                                                      \
        const i32x4* hp = (const i32x4*)hq[P];                                 \
        /* MFMA: gates i,f on the matrix pipe */                               \
        i32x4 a0 = hp[kg], a1 = hp[4 + kg], a2 = hp[8 + kg], a3 = hp[12 + kg]; \
        acc[0].x = 0; acc[1].x = 0; acc[2].x = 0; acc[3].x = 0;                \
        _Pragma("unroll") for (int ti = 0; ti < 4; ++ti)                       \
            acc[ti] = __builtin_amdgcn_mfma_i32_16x16x64_i8(a0, bfr[ti][0], acc[ti], 0, 0, 0); \
        _Pragma("unroll") for (int ti = 0; ti < 4; ++ti)                       \
            acc[ti] = __builtin_amdgcn_mfma_i32_16x16x64_i8(a1, bfr[ti][1], acc[ti], 0, 0, 0); \
        _Pragma("unroll") for (int ti = 0; ti < 4; ++ti)                       \
            acc[ti] = __builtin_amdgcn_mfma_i32_16x16x64_i8(a2, bfr[ti][2], acc[ti], 0, 0, 0); \
        _Pragma("unroll") for (int ti = 0; ti < 4; ++ti)                       \
            acc[ti] = __builtin_amdgcn_mfma_i32_16x16x64_i8(a3, bfr[ti][3], acc[ti], 0, 0, 0); \
        /* dots: gates z,o on the VALU pipe; h via wave-uniform LDS broadcast */ \
        int da0 = 0, da1 = 0, da2 = 0, da3 = 0;                                \
        _Pragma("unroll") for (int kb = 0; kb < 4; ++kb) {                     \
            i32x4 ha = hp[kb * 4 + 0];                                         \
            i32x4 hb = hp[kb * 4 + 1];                                         \
            i32x4 hc = hp[kb * 4 + 2];                                         \
            i32x4 hd4 = hp[kb * 4 + 3];                                        \
            da0 = dot4i8(da0, w[kb * 16 + 0], ha.x);                           \
            da1 = dot4i8(da1, w[kb * 16 + 1], ha.y);                           \
            da2 = dot4i8(da2, w[kb * 16 + 2], ha.z);                           \
            da3 = dot4i8(da3, w[kb * 16 + 3], ha.w);                           \
            da0 = dot4i8(da0, w[kb * 16 + 4], hb.x);                           \
            da1 = dot4i8(da1, w[kb * 16 + 5], hb.y);                           \
            da2 = dot4i8(da2, w[kb * 16 + 6], hb.z);                           \
            da3 = dot4i8(da3, w[kb * 16 + 7], hb.w);                           \
            da0 = dot4i8(da0, w[kb * 16 + 8], hc.x);                           \
            da1 = dot4i8(da1, w[kb * 16 + 9], hc.y);                           \
            da2 = dot4i8(da2, w[kb * 16 + 10], hc.z);                          \
            da3 = dot4i8(da3, w[kb * 16 + 11], hc.w);                          \
            da0 = dot4i8(da0, w[kb * 16 + 12], hd4.x);                         \
            da1 = dot4i8(da1, w[kb * 16 + 13], hd4.y);                         \
            da2 = dot4i8(da2, w[kb * 16 + 14], hd4.z);                         \
            da3 = dot4i8(da3, w[kb * 16 + 15], hd4.w);                         \
        }                                                                      \
        int adot = (da0 + da1) + (da2 + da3);                                  \
        /* in-wave gather: i,f from MFMA row-0 lanes, o from upper half */     \
        int ri0 = __shfl(acc[0].x, cl);                                        \
        int ri1 = __shfl(acc[1].x, cl);                                        \
        int rf0 = __shfl(acc[2].x, cl);                                        \
        int rf1 = __shfl(acc[3].x, cl);                                        \
        int roX = __shfl(adot, l | 32);                                        \
        int ri_raw = (l & 16) ? ri1 : ri0;                                     \
        int rf_raw = (l & 16) ? rf1 : rf0;                                     \
        float rawi = (G0) + (float)ri_raw * cmi + bi;                          \
        float rawf = (G1) + (float)rf_raw * cmf + bf_;                         \
        float rawz = (G2) + (float)adot * cmz + bz;                            \
        float rawo = (G3) + (float)roX * cmo + bo;                             \
        float lsf = fminf(rawf, 0.f) - __logf(1.f + __expf(-fabsf(rawf)));     \
        float lfm = mstate + lsf;                                              \
        float mn = fmaxf(rawi, lfm);                                           \
        float ig = __expf(rawi - mn);                                          \
        float fg = __expf(lfm - mn);                                           \
        float az_ = fabsf(rawz);                                               \
        float e2 = __expf(-2.f * az_);                                         \
        float th = (1.f - e2) / (1.f + e2);                                    \
        th = rawz < 0.f ? -th : th;                                            \
        c_ = fg * c_ + ig * th;                                                \
        n_ = fg * n_ + ig;                                                     \
        mstate = mn;                                                           \
        float so = 1.f / (1.f + __expf(-rawo));                                \
        float hv = so * c_ / n_;                                               \
        if (l < 32) {                                                          \
            ybase[(size_t)(SCUR)*DH + d] = hv;                                 \
            hq[(P) ^ 1][d] = (signed char)(int)rintf(hv * 127.f);              \
        }                                                                      \
        G0 = p0; G1 = p1; G2 = p2; G3 = p3;                                    \
        wg_barrier();                                                          \
    }

    for (int s = 0; s < SS; s += 2) {
        SCAN_STEP(0, gA0, gA1, gA2, gA3, s)
        SCAN_STEP(1, gB0, gB1, gB2, gB3, s + 1)
    }
#undef SCAN_STEP
}

// ---------------- multihead layernorm + transpose ----------------
__global__ void k_ln(const float* __restrict__ y, const float* __restrict__ gsc,
                     const float* __restrict__ gbi, float* __restrict__ out) {
    int bid = blockIdx.x;  // bh*2048 + s
    int s = bid & (SS - 1);
    int bh = bid >> 11;
    int b = bh >> 2, h = bh & 3;
    int d = threadIdx.x;
    float v = y[(size_t)bid * DH + d];
    float s1 = v, s2 = v * v;
    for (int off = 32; off; off >>= 1) {
        s1 += __shfl_xor(s1, off);
        s2 += __shfl_xor(s2, off);
    }
    __shared__ float a1[4], a2[4];
    int wv = threadIdx.x >> 6, ln = threadIdx.x & 63;
    if (ln == 0) { a1[wv] = s1; a2[wv] = s2; }
    __syncthreads();
    s1 = a1[0] + a1[1] + a1[2] + a1[3];
    s2 = a2[0] + a2[1] + a2[2] + a2[3];
    float mu = s1 * (1.f / 256.f);
    float var = s2 * (1.f / 256.f) - mu * mu;
    float rs = rsqrtf(var + 1e-6f);
    float o = (v - mu) * rs * gsc[h * DH + d] + gbi[h * DH + d];
    out[((size_t)(b * SS + s)) * DMODEL + h * DH + d] = o;
}

extern "C" void kernel_launch(void* const* d_in, const int* in_sizes, int n_in,
                              void* d_out, int out_size, void* d_ws, size_t ws_size,
                              hipStream_t stream) {
    (void)in_sizes; (void)n_in; (void)out_size; (void)ws_size;
    const float* x = (const float*)d_in[0];
    const float* cw = (const float*)d_in[1];
    const float* cb = (const float*)d_in[2];
    const float* wi = (const float*)d_in[3];
    const float* wf = (const float*)d_in[4];
    const float* wz = (const float*)d_in[5];
    const float* wo = (const float*)d_in[6];
    const float* R = (const float*)d_in[7];
    const float* cbias = (const float*)d_in[8];
    const float* gsc = (const float*)d_in[9];
    const float* gbi = (const float*)d_in[10];
    float* out = (float*)d_out;

    char* ws = (char*)d_ws;
    float* xc = (float*)ws;                           // 33,554,432 B
    float* gates = (float*)(ws + 33554432ull);        // 134,217,728 B
    float* yb = (float*)(ws + 167772160ull);          // 33,554,432 B
    int* Wq = (int*)(ws + 201326592ull);              // 1,048,576 B
    float* scales = (float*)(ws + 202375168ull);      // 16,384 B

    k_prep<<<1024, 256, 0, stream>>>(R, Wq, scales);
    k_conv<<<BB * SS, 256, 0, stream>>>(x, cw, cb, xc);
    k_gemm<<<dim3(128, 8, 8), 256, 0, stream>>>(x, xc, wi, wf, wz, wo, gates);
    k_scan<<<16, 512, 0, stream>>>(gates, Wq, scales, cbias, yb);
    k_ln<<<BB * SS * NH, 256, 0, stream>>>(yb, gsc, gbi, out);
}

// Round 10
// 2198.360 us; speedup vs baseline: 1.2021x; 1.2021x over previous
//
#include <hip/hip_runtime.h>
#include <hip/hip_bf16.h>

#define NH 4
#define DH 256
#define DMODEL 1024
#define BB 4
#define SS 2048

typedef __attribute__((ext_vector_type(4))) float f32x4;
typedef __attribute__((ext_vector_type(8))) short bf16x8;
typedef __attribute__((ext_vector_type(4))) int i32x4;

__device__ __forceinline__ int dot4i8(int acc, int a, int b) {
#if __has_builtin(__builtin_amdgcn_sdot4)
    return __builtin_amdgcn_sdot4(a, b, acc, false);
#else
#pragma unroll
    for (int i = 0; i < 4; ++i) {
        int av = (a << (24 - 8 * i)) >> 24;
        int bv = (b << (24 - 8 * i)) >> 24;
        acc += av * bv;
    }
    return acc;
#endif
}

// Raw workgroup barrier: orders LDS only; global loads/stores stay in flight.
__device__ __forceinline__ void wg_barrier() {
    asm volatile("s_waitcnt lgkmcnt(0)" ::: "memory");
    __builtin_amdgcn_s_barrier();
}

// exchange with lane^1 via DPP quad_perm (VALU pipe, not LDS)
__device__ __forceinline__ float xor1_f32(float v) {
    int r = __builtin_amdgcn_update_dpp(0, __float_as_int(v), 0xB1, 0xF, 0xF, true);
    return __int_as_float(r);
}

// ---------------- conv + swish ----------------
__global__ void k_conv(const float* __restrict__ x, const float* __restrict__ cw,
                       const float* __restrict__ cb, float* __restrict__ xc) {
    int bs = blockIdx.x;              // b*2048 + s
    int s = bs & (SS - 1);
    const float* xrow = x + (size_t)bs * DMODEL;
#pragma unroll
    for (int dd = 0; dd < 4; ++dd) {
        int d = threadIdx.x + dd * 256;
        float w0 = cw[d * 4 + 0], w1 = cw[d * 4 + 1], w2 = cw[d * 4 + 2], w3 = cw[d * 4 + 3];
        float acc = cb[d] + w3 * xrow[d];
        if (s >= 1) acc += w2 * xrow[d - DMODEL];
        if (s >= 2) acc += w1 * xrow[d - 2 * DMODEL];
        if (s >= 3) acc += w0 * xrow[d - 3 * DMODEL];
        float sig = 1.f / (1.f + __expf(-acc));
        xc[(size_t)bs * DMODEL + d] = acc * sig;
    }
}

// ---------------- headwise projections (bf16 MFMA GEMM) ----------------
// gates layout: [b][h][s][g][d]
__global__ void k_gemm(const float* __restrict__ x, const float* __restrict__ xc,
                       const float* __restrict__ wi, const float* __restrict__ wf,
                       const float* __restrict__ wz, const float* __restrict__ wo,
                       float* __restrict__ gates) {
    int h = blockIdx.z >> 1, pair = blockIdx.z & 1;
    const float* A = pair ? x : xc;
    int n0 = blockIdx.y * 64;  // in [0,512)
    const float* W = (n0 < 256) ? (pair ? wz : wi) : (pair ? wo : wf);
    int nl = n0 & 255;
    int m0 = blockIdx.x * 64;

    __shared__ __align__(16) __hip_bfloat16 Al[64][72];
    __shared__ __align__(16) __hip_bfloat16 Bl[64][72];

    int tid = threadIdx.x;
    int lane = tid & 63, wv = tid >> 6;
    f32x4 acc[4] = {};

    for (int k0 = 0; k0 < 256; k0 += 64) {
        __syncthreads();
#pragma unroll
        for (int i = 0; i < 4; ++i) {
            int f4 = tid + i * 256;
            int r = f4 >> 4, c4 = (f4 & 15) * 4;
            const float* srcA = A + (size_t)(m0 + r) * DMODEL + h * DH + k0 + c4;
            float4 v = *(const float4*)srcA;
            Al[r][c4 + 0] = __float2bfloat16(v.x);
            Al[r][c4 + 1] = __float2bfloat16(v.y);
            Al[r][c4 + 2] = __float2bfloat16(v.z);
            Al[r][c4 + 3] = __float2bfloat16(v.w);
            const float* srcB = W + (size_t)(h * DH + nl + r) * DH + k0 + c4;
            float4 u = *(const float4*)srcB;
            Bl[r][c4 + 0] = __float2bfloat16(u.x);
            Bl[r][c4 + 1] = __float2bfloat16(u.y);
            Bl[r][c4 + 2] = __float2bfloat16(u.z);
            Bl[r][c4 + 3] = __float2bfloat16(u.w);
        }
        __syncthreads();
#pragma unroll
        for (int kk = 0; kk < 64; kk += 32) {
            bf16x8 a = *(const bf16x8*)&Al[wv * 16 + (lane & 15)][kk + (lane >> 4) * 8];
#pragma unroll
            for (int nt = 0; nt < 4; ++nt) {
                bf16x8 bfr = *(const bf16x8*)&Bl[nt * 16 + (lane & 15)][kk + (lane >> 4) * 8];
                acc[nt] = __builtin_amdgcn_mfma_f32_16x16x32_bf16(a, bfr, acc[nt], 0, 0, 0);
            }
        }
    }
#pragma unroll
    for (int nt = 0; nt < 4; ++nt)
#pragma unroll
        for (int r = 0; r < 4; ++r) {
            int m = m0 + wv * 16 + (lane >> 4) * 4 + r;
            int n = n0 + nt * 16 + (lane & 15);
            int b = m >> 11, s = m & (SS - 1);
            int g = pair * 2 + (n >> 8), d = n & 255;
            gates[((((size_t)(b * NH + h)) * SS + s) * 4 + g) * DH + d] = acc[nt][r];
        }
}

// ---------------- weight prep: per-column int8 quantization of R ----------------
// Wq[(h*64 + j)*1024 + col]: 4 i8 packed (byte i = R[h][4j+i][col] quantized)
__global__ void k_prep(const float* __restrict__ R, int* __restrict__ Wq,
                       float* __restrict__ scales) {
    int colid = blockIdx.x * 4 + (threadIdx.x >> 6);  // 0..4095
    int lane = threadIdx.x & 63;
    int h = colid >> 10, k = colid & 1023;
    const float* base = R + (size_t)h * 256 * 1024 + k;
    float v[4];
    float mx = 0.f;
#pragma unroll
    for (int i = 0; i < 4; ++i) {
        v[i] = base[(size_t)(lane * 4 + i) * 1024];
        mx = fmaxf(mx, fabsf(v[i]));
    }
    for (int off = 32; off; off >>= 1) mx = fmaxf(mx, __shfl_xor(mx, off));
    mx = fmaxf(mx, 1e-30f);
    float scale = mx * (1.f / 127.f);
    float inv = 127.f / mx;
    int pk = 0;
#pragma unroll
    for (int i = 0; i < 4; ++i) {
        int q = (int)rintf(v[i] * inv);
        q = max(-127, min(127, q));
        pk |= (q & 255) << (8 * i);
    }
    Wq[(h * 64 + lane) * 1024 + k] = pk;
    if (lane == 0) scales[h * 1024 + k] = scale;
}

// ---------------- the sequential sLSTM scan ----------------
// Round-7 structure with the weight ARRAYS replaced by 128 individually-NAMED
// scalar variables. Theory (rounds 0/3/7/8 evidence): LLVM offloads local
// ARRAYS that feed v_dot4 (AGPR home + copy per use; VGPR_Count stuck at
// 52-116 for any budget). Named scalars are independent SSA values -- no
// array object to shelve; the RA allocates them like ordinary live values.
// Footprint: 128 weights + ~60 live ~= 190 <= 256-reg cap at 2 waves/SIMD.
// Geometry identical to round 7: 512 threads, t = (d = t>>1, pair = t&1);
// pair0 owns {i[d], z[d]}, pair1 owns {f[d], o[d]}; DPP lane^1 exchange;
// one raw barrier/step; hq double-buffered; distance-1 gate prefetch.
// 4 independent dot accumulators (integer adds -- bit-exact, same sums).
#define FOR64(X) \
    X(0) X(1) X(2) X(3) X(4) X(5) X(6) X(7) X(8) X(9) X(10) X(11) X(12) X(13) \
    X(14) X(15) X(16) X(17) X(18) X(19) X(20) X(21) X(22) X(23) X(24) X(25)   \
    X(26) X(27) X(28) X(29) X(30) X(31) X(32) X(33) X(34) X(35) X(36) X(37)   \
    X(38) X(39) X(40) X(41) X(42) X(43) X(44) X(45) X(46) X(47) X(48) X(49)   \
    X(50) X(51) X(52) X(53) X(54) X(55) X(56) X(57) X(58) X(59) X(60) X(61)   \
    X(62) X(63)

__launch_bounds__(512, 2)
__global__ void k_scan(const float* __restrict__ gates, const int* __restrict__ Wq,
                       const float* __restrict__ scales, const float* __restrict__ bias,
                       float* __restrict__ y) {
    int bh = blockIdx.x;
    int h = bh & 3;
    int t = threadIdx.x;
    int d = t >> 1, pair = t & 1;

    __shared__ __align__(16) signed char hq[2][256];

    int col0 = pair * 256 + d;   // i[d] or f[d]
    int col1 = col0 + 512;       // z[d] or o[d]

    // 128 named weight scalars
#define DECLW(j) int w0_##j, w1_##j;
    FOR64(DECLW)
#undef DECLW
#define LOADW(j)                                   \
    w0_##j = Wq[(h * 64 + (j)) * 1024 + col0];     \
    w1_##j = Wq[(h * 64 + (j)) * 1024 + col1];
    FOR64(LOADW)
#undef LOADW

    float cm0 = scales[h * 1024 + col0] * (1.f / 127.f);
    float cm1 = scales[h * 1024 + col1] * (1.f / 127.f);
    float b0 = bias[(pair * NH + h) * DH + d];        // bias i or f
    float b1 = bias[((2 + pair) * NH + h) * DH + d];  // bias z or o

    float c_ = 0.f, n_ = 0.f, mstate = 0.f;
    const float* gbase = gates + (size_t)bh * SS * 1024;
    float* ybase = y + (size_t)bh * SS * DH + d;

    if (t < 32) ((i32x4*)hq)[t] = (i32x4){0, 0, 0, 0};
    __syncthreads();

    float g0 = gbase[col0], g1 = gbase[col1];
    int p = 0;

    for (int s = 0; s < SS; ++s) {
        // distance-1 prefetch of next step's gates (rides across the barrier)
        int sp = (s + 1 < SS) ? s + 1 : SS - 1;
        float pre0 = gbase[(size_t)sp * 1024 + col0];
        float pre1 = gbase[(size_t)sp * 1024 + col1];

        const i32x4* hp = (const i32x4*)hq[p];
        int a0 = 0, a1 = 0, b0acc = 0, b1acc = 0;
        // chunk q covers weight dwords 4q..4q+3 against h dwords 4q..4q+3
#define DOTC(q, j0, j1, j2, j3)                                        \
        {                                                              \
            i32x4 hv = hp[q];                                          \
            a0 = dot4i8(a0, w0_##j0, hv.x);                            \
            a1 = dot4i8(a1, w1_##j0, hv.x);                            \
            b0acc = dot4i8(b0acc, w0_##j1, hv.y);                      \
            b1acc = dot4i8(b1acc, w1_##j1, hv.y);                      \
            a0 = dot4i8(a0, w0_##j2, hv.z);                            \
            a1 = dot4i8(a1, w1_##j2, hv.z);                            \
            b0acc = dot4i8(b0acc, w0_##j3, hv.w);                      \
            b1acc = dot4i8(b1acc, w1_##j3, hv.w);                      \
        }
        DOTC(0, 0, 1, 2, 3)
        DOTC(1, 4, 5, 6, 7)
        DOTC(2, 8, 9, 10, 11)
        DOTC(3, 12, 13, 14, 15)
        DOTC(4, 16, 17, 18, 19)
        DOTC(5, 20, 21, 22, 23)
        DOTC(6, 24, 25, 26, 27)
        DOTC(7, 28, 29, 30, 31)
        DOTC(8, 32, 33, 34, 35)
        DOTC(9, 36, 37, 38, 39)
        DOTC(10, 40, 41, 42, 43)
        DOTC(11, 44, 45, 46, 47)
        DOTC(12, 48, 49, 50, 51)
        DOTC(13, 52, 53, 54, 55)
        DOTC(14, 56, 57, 58, 59)
        DOTC(15, 60, 61, 62, 63)
#undef DOTC
        int asum = a0 + b0acc;
        int bsum = a1 + b1acc;

        float rawA = g0 + (float)asum * cm0 + b0;   // i (pair0) or f (pair1)
        float rawB = g1 + (float)bsum * cm1 + b1;   // z (pair0) or o (pair1)
        float recvA = xor1_f32(rawA);
        float recvB = xor1_f32(rawB);
        float rawi = pair ? recvA : rawA;
        float rawf = pair ? rawA : recvA;
        float rawz = pair ? recvB : rawB;
        float rawo = pair ? rawB : recvB;

        float lsf = fminf(rawf, 0.f) - __logf(1.f + __expf(-fabsf(rawf)));
        float lfm = mstate + lsf;
        float mn = fmaxf(rawi, lfm);
        float ig = __expf(rawi - mn);
        float fg = __expf(lfm - mn);
        float az = fabsf(rawz);
        float e2 = __expf(-2.f * az);
        float th = (1.f - e2) / (1.f + e2);
        th = rawz < 0.f ? -th : th;
        c_ = fg * c_ + ig * th;
        n_ = fg * n_ + ig;
        mstate = mn;
        float so = 1.f / (1.f + __expf(-rawo));
        float hv2 = so * c_ / n_;

        if (!pair) {
            ybase[(size_t)s * DH] = hv2;
            hq[p ^ 1][d] = (signed char)(int)rintf(hv2 * 127.f);
        }

        g0 = pre0;
        g1 = pre1;
        p ^= 1;
        wg_barrier();
    }
}

// ---------------- multihead layernorm + transpose ----------------
__global__ void k_ln(const float* __restrict__ y, const float* __restrict__ gsc,
                     const float* __restrict__ gbi, float* __restrict__ out) {
    int bid = blockIdx.x;  // bh*2048 + s
    int s = bid & (SS - 1);
    int bh = bid >> 11;
    int b = bh >> 2, h = bh & 3;
    int d = threadIdx.x;
    float v = y[(size_t)bid * DH + d];
    float s1 = v, s2 = v * v;
    for (int off = 32; off; off >>= 1) {
        s1 += __shfl_xor(s1, off);
        s2 += __shfl_xor(s2, off);
    }
    __shared__ float a1[4], a2[4];
    int wv = threadIdx.x >> 6, ln = threadIdx.x & 63;
    if (ln == 0) { a1[wv] = s1; a2[wv] = s2; }
    __syncthreads();
    s1 = a1[0] + a1[1] + a1[2] + a1[3];
    s2 = a2[0] + a2[1] + a2[2] + a2[3];
    float mu = s1 * (1.f / 256.f);
    float var = s2 * (1.f / 256.f) - mu * mu;
    float rs = rsqrtf(var + 1e-6f);
    float o = (v - mu) * rs * gsc[h * DH + d] + gbi[h * DH + d];
    out[((size_t)(b * SS + s)) * DMODEL + h * DH + d] = o;
}

extern "C" void kernel_launch(void* const* d_in, const int* in_sizes, int n_in,
                              void* d_out, int out_size, void* d_ws, size_t ws_size,
                              hipStream_t stream) {
    (void)in_sizes; (void)n_in; (void)out_size; (void)ws_size;
    const float* x = (const float*)d_in[0];
    const float* cw = (const float*)d_in[1];
    const float* cb = (const float*)d_in[2];
    const float* wi = (const float*)d_in[3];
    const float* wf = (const float*)d_in[4];
    const float* wz = (const float*)d_in[5];
    const float* wo = (const float*)d_in[6];
    const float* R = (const float*)d_in[7];
    const float* cbias = (const float*)d_in[8];
    const float* gsc = (const float*)d_in[9];
    const float* gbi = (const float*)d_in[10];
    float* out = (float*)d_out;

    char* ws = (char*)d_ws;
    float* xc = (float*)ws;                           // 33,554,432 B
    float* gates = (float*)(ws + 33554432ull);        // 134,217,728 B
    float* yb = (float*)(ws + 167772160ull);          // 33,554,432 B
    int* Wq = (int*)(ws + 201326592ull);              // 1,048,576 B
    float* scales = (float*)(ws + 202375168ull);      // 16,384 B

    k_prep<<<1024, 256, 0, stream>>>(R, Wq, scales);
    k_conv<<<BB * SS, 256, 0, stream>>>(x, cw, cb, xc);
    k_gemm<<<dim3(128, 8, 8), 256, 0, stream>>>(x, xc, wi, wf, wz, wo, gates);
    k_scan<<<16, 512, 0, stream>>>(gates, Wq, scales, cbias, yb);
    k_ln<<<BB * SS * NH, 256, 0, stream>>>(yb, gsc, gbi, out);
}

// Round 11
// 2105.976 us; speedup vs baseline: 1.2548x; 1.0439x over previous
//
#include <hip/hip_runtime.h>
#include <hip/hip_bf16.h>

#define NH 4
#define DH 256
#define DMODEL 1024
#define BB 4
#define SS 2048

typedef __attribute__((ext_vector_type(4))) float f32x4;
typedef __attribute__((ext_vector_type(8))) short bf16x8;
typedef __attribute__((ext_vector_type(4))) int i32x4;

__device__ __forceinline__ int dot4i8(int acc, int a, int b) {
#if __has_builtin(__builtin_amdgcn_sdot4)
    return __builtin_amdgcn_sdot4(a, b, acc, false);
#else
#pragma unroll
    for (int i = 0; i < 4; ++i) {
        int av = (a << (24 - 8 * i)) >> 24;
        int bv = (b << (24 - 8 * i)) >> 24;
        acc += av * bv;
    }
    return acc;
#endif
}

// ---------------- conv + swish ----------------
__global__ void k_conv(const float* __restrict__ x, const float* __restrict__ cw,
                       const float* __restrict__ cb, float* __restrict__ xc) {
    int bs = blockIdx.x;              // b*2048 + s
    int s = bs & (SS - 1);
    const float* xrow = x + (size_t)bs * DMODEL;
#pragma unroll
    for (int dd = 0; dd < 4; ++dd) {
        int d = threadIdx.x + dd * 256;
        float w0 = cw[d * 4 + 0], w1 = cw[d * 4 + 1], w2 = cw[d * 4 + 2], w3 = cw[d * 4 + 3];
        float acc = cb[d] + w3 * xrow[d];
        if (s >= 1) acc += w2 * xrow[d - DMODEL];
        if (s >= 2) acc += w1 * xrow[d - 2 * DMODEL];
        if (s >= 3) acc += w0 * xrow[d - 3 * DMODEL];
        float sig = 1.f / (1.f + __expf(-acc));
        xc[(size_t)bs * DMODEL + d] = acc * sig;
    }
}

// ---------------- headwise projections (bf16 MFMA GEMM) ----------------
// grid: (M/64=128, 512/64=8, 8 instances). instance z = h*2 + pair.
// pair0: {i,f} from x_conv ; pair1: {z,o} from x.
__global__ void k_gemm(const float* __restrict__ x, const float* __restrict__ xc,
                       const float* __restrict__ wi, const float* __restrict__ wf,
                       const float* __restrict__ wz, const float* __restrict__ wo,
                       float* __restrict__ gates) {
    int h = blockIdx.z >> 1, pair = blockIdx.z & 1;
    const float* A = pair ? x : xc;
    int n0 = blockIdx.y * 64;  // in [0,512)
    const float* W = (n0 < 256) ? (pair ? wz : wi) : (pair ? wo : wf);
    int nl = n0 & 255;
    int m0 = blockIdx.x * 64;

    __shared__ __align__(16) __hip_bfloat16 Al[64][72];
    __shared__ __align__(16) __hip_bfloat16 Bl[64][72];

    int tid = threadIdx.x;
    int lane = tid & 63, wv = tid >> 6;
    f32x4 acc[4] = {};

    for (int k0 = 0; k0 < 256; k0 += 64) {
        __syncthreads();
#pragma unroll
        for (int i = 0; i < 4; ++i) {
            int f4 = tid + i * 256;
            int r = f4 >> 4, c4 = (f4 & 15) * 4;
            const float* srcA = A + (size_t)(m0 + r) * DMODEL + h * DH + k0 + c4;
            float4 v = *(const float4*)srcA;
            Al[r][c4 + 0] = __float2bfloat16(v.x);
            Al[r][c4 + 1] = __float2bfloat16(v.y);
            Al[r][c4 + 2] = __float2bfloat16(v.z);
            Al[r][c4 + 3] = __float2bfloat16(v.w);
            const float* srcB = W + (size_t)(h * DH + nl + r) * DH + k0 + c4;
            float4 u = *(const float4*)srcB;
            Bl[r][c4 + 0] = __float2bfloat16(u.x);
            Bl[r][c4 + 1] = __float2bfloat16(u.y);
            Bl[r][c4 + 2] = __float2bfloat16(u.z);
            Bl[r][c4 + 3] = __float2bfloat16(u.w);
        }
        __syncthreads();
#pragma unroll
        for (int kk = 0; kk < 64; kk += 32) {
            bf16x8 a = *(const bf16x8*)&Al[wv * 16 + (lane & 15)][kk + (lane >> 4) * 8];
#pragma unroll
            for (int nt = 0; nt < 4; ++nt) {
                bf16x8 bfr = *(const bf16x8*)&Bl[nt * 16 + (lane & 15)][kk + (lane >> 4) * 8];
                acc[nt] = __builtin_amdgcn_mfma_f32_16x16x32_bf16(a, bfr, acc[nt], 0, 0, 0);
            }
        }
    }
    // epilogue: gates[b][h][s][g][d]
#pragma unroll
    for (int nt = 0; nt < 4; ++nt)
#pragma unroll
        for (int r = 0; r < 4; ++r) {
            int m = m0 + wv * 16 + (lane >> 4) * 4 + r;
            int n = n0 + nt * 16 + (lane & 15);
            int b = m >> 11, s = m & (SS - 1);
            int g = pair * 2 + (n >> 8), d = n & 255;
            gates[((((size_t)(b * NH + h)) * SS + s) * 4 + g) * DH + d] = acc[nt][r];
        }
}

// ---------------- weight prep: per-column int8 quantization of R ----------------
// one wave per column k of head h. lane covers d = 4*lane .. 4*lane+3.
__global__ void k_prep(const float* __restrict__ R, int* __restrict__ Wq,
                       float* __restrict__ scales) {
    int colid = blockIdx.x * 4 + (threadIdx.x >> 6);  // 0..4095
    int lane = threadIdx.x & 63;
    int h = colid >> 10, k = colid & 1023;
    const float* base = R + (size_t)h * 256 * 1024 + k;
    float v[4];
    float mx = 0.f;
#pragma unroll
    for (int i = 0; i < 4; ++i) {
        v[i] = base[(size_t)(lane * 4 + i) * 1024];
        mx = fmaxf(mx, fabsf(v[i]));
    }
    for (int off = 32; off; off >>= 1) mx = fmaxf(mx, __shfl_xor(mx, off));
    mx = fmaxf(mx, 1e-30f);
    float scale = mx * (1.f / 127.f);
    float inv = 127.f / mx;
    int pk = 0;
#pragma unroll
    for (int i = 0; i < 4; ++i) {
        int q = (int)rintf(v[i] * inv);
        q = max(-127, min(127, q));
        pk |= (q & 255) << (8 * i);
    }
    Wq[(h * 64 + lane) * 1024 + k] = pk;
    if (lane == 0) scales[h * 1024 + k] = scale;
}

// ---------------- the sequential sLSTM scan ----------------
// 16 blocks, one per (b,h). 1024 threads; thread t owns rec column t.
// Weights int8 register-resident (64 dwords/thread). h quantized to i8 (|h|<1).
// NOTE (rounds 1-10 post-mortems): this structure is the measured floor for
// this toolchain (~1959 us). All variants -- raw barriers, prefetch, K-split,
// pair-split, i8-MFMA, hybrid pipes, launch-bounds/pins/named-scalar register
// levers -- landed 1991-2980 us. The allocator's sdot4-array offload
// (VGPR_Count invariant at any budget) plus the per-step LDS broadcast and
// barrier latency form a ~2300 cyc/step floor that no HIP-source expression
// tested here breaks. Do not re-tune without new toolchain evidence.
__launch_bounds__(1024, 4)
__global__ void k_scan(const float* __restrict__ gates, const int* __restrict__ Wq,
                       const float* __restrict__ scales, const float* __restrict__ bias,
                       float* __restrict__ y) {
    int bh = blockIdx.x;
    int h = bh & 3;
    int t = threadIdx.x;

    __shared__ __align__(16) signed char hq[256];
    __shared__ float rec[1024];

    int w[64];
#pragma unroll
    for (int j = 0; j < 64; ++j) w[j] = Wq[(h * 64 + j) * 1024 + t];
    float colmul = scales[h * 1024 + t] * (1.f / 127.f);

    float c = 0.f, n = 0.f, mstate = 0.f;
    float bi = 0.f, bf_ = 0.f, bz = 0.f, bo = 0.f;
    int d = t;
    if (t < 256) {
        bi = bias[(0 * NH + h) * DH + d];
        bf_ = bias[(1 * NH + h) * DH + d];
        bz = bias[(2 * NH + h) * DH + d];
        bo = bias[(3 * NH + h) * DH + d];
    }
    if (t < 16) ((i32x4*)hq)[t] = (i32x4){0, 0, 0, 0};
    const float* gbase = gates + (size_t)bh * SS * 1024;
    float* ybase = y + (size_t)bh * SS * DH;
    __syncthreads();

    for (int s = 0; s < SS; ++s) {
        float gi = 0.f, gf = 0.f, gz = 0.f, go = 0.f;
        if (t < 256) {
            const float* gp = gbase + (size_t)s * 1024 + d;
            gi = gp[0]; gf = gp[256]; gz = gp[512]; go = gp[768];
        }
        // rec = (i8 h) . (i8 W column t)
        int acc = 0;
#pragma unroll
        for (int g4 = 0; g4 < 4; ++g4) {
            i32x4 h0 = ((const i32x4*)hq)[g4 * 4 + 0];
            i32x4 h1 = ((const i32x4*)hq)[g4 * 4 + 1];
            i32x4 h2 = ((const i32x4*)hq)[g4 * 4 + 2];
            i32x4 h3 = ((const i32x4*)hq)[g4 * 4 + 3];
            acc = dot4i8(acc, w[g4 * 16 + 0], h0.x);
            acc = dot4i8(acc, w[g4 * 16 + 1], h0.y);
            acc = dot4i8(acc, w[g4 * 16 + 2], h0.z);
            acc = dot4i8(acc, w[g4 * 16 + 3], h0.w);
            acc = dot4i8(acc, w[g4 * 16 + 4], h1.x);
            acc = dot4i8(acc, w[g4 * 16 + 5], h1.y);
            acc = dot4i8(acc, w[g4 * 16 + 6], h1.z);
            acc = dot4i8(acc, w[g4 * 16 + 7], h1.w);
            acc = dot4i8(acc, w[g4 * 16 + 8], h2.x);
            acc = dot4i8(acc, w[g4 * 16 + 9], h2.y);
            acc = dot4i8(acc, w[g4 * 16 + 10], h2.z);
            acc = dot4i8(acc, w[g4 * 16 + 11], h2.w);
            acc = dot4i8(acc, w[g4 * 16 + 12], h3.x);
            acc = dot4i8(acc, w[g4 * 16 + 13], h3.y);
            acc = dot4i8(acc, w[g4 * 16 + 14], h3.z);
            acc = dot4i8(acc, w[g4 * 16 + 15], h3.w);
        }
        rec[t] = (float)acc * colmul;
        __syncthreads();
        if (t < 256) {
            float ri = rec[d], rf = rec[256 + d], rz = rec[512 + d], ro = rec[768 + d];
            float rawi = gi + ri + bi;
            float rawf = gf + rf + bf_;
            float rawz = gz + rz + bz;
            float rawo = go + ro + bo;
            // log_sigmoid(rawf) = min(rawf,0) - log1p(exp(-|rawf|))
            float lsf = fminf(rawf, 0.f) - __logf(1.f + __expf(-fabsf(rawf)));
            float lfm = mstate + lsf;
            float mn = fmaxf(rawi, lfm);
            float ig = __expf(rawi - mn);
            float fg = __expf(lfm - mn);
            float az = fabsf(rawz);
            float e2 = __expf(-2.f * az);
            float th = (1.f - e2) / (1.f + e2);
            th = rawz < 0.f ? -th : th;
            c = fg * c + ig * th;
            n = fg * n + ig;
            mstate = mn;
            float so = 1.f / (1.f + __expf(-rawo));
            float hv = so * c / n;
            ybase[(size_t)s * DH + d] = hv;
            int q = (int)rintf(hv * 127.f);
            hq[d] = (signed char)q;
        }
        __syncthreads();
    }
}

// ---------------- multihead layernorm + transpose ----------------
__global__ void k_ln(const float* __restrict__ y, const float* __restrict__ gsc,
                     const float* __restrict__ gbi, float* __restrict__ out) {
    int bid = blockIdx.x;  // bh*2048 + s
    int s = bid & (SS - 1);
    int bh = bid >> 11;
    int b = bh >> 2, h = bh & 3;
    int d = threadIdx.x;
    float v = y[(size_t)bid * DH + d];
    float s1 = v, s2 = v * v;
    for (int off = 32; off; off >>= 1) {
        s1 += __shfl_xor(s1, off);
        s2 += __shfl_xor(s2, off);
    }
    __shared__ float a1[4], a2[4];
    int wv = threadIdx.x >> 6, ln = threadIdx.x & 63;
    if (ln == 0) { a1[wv] = s1; a2[wv] = s2; }
    __syncthreads();
    s1 = a1[0] + a1[1] + a1[2] + a1[3];
    s2 = a2[0] + a2[1] + a2[2] + a2[3];
    float mu = s1 * (1.f / 256.f);
    float var = s2 * (1.f / 256.f) - mu * mu;
    float rs = rsqrtf(var + 1e-6f);
    float o = (v - mu) * rs * gsc[h * DH + d] + gbi[h * DH + d];
    out[((size_t)(b * SS + s)) * DMODEL + h * DH + d] = o;
}

extern "C" void kernel_launch(void* const* d_in, const int* in_sizes, int n_in,
                              void* d_out, int out_size, void* d_ws, size_t ws_size,
                              hipStream_t stream) {
    (void)in_sizes; (void)n_in; (void)out_size; (void)ws_size;
    const float* x = (const float*)d_in[0];
    const float* cw = (const float*)d_in[1];
    const float* cb = (const float*)d_in[2];
    const float* wi = (const float*)d_in[3];
    const float* wf = (const float*)d_in[4];
    const float* wz = (const float*)d_in[5];
    const float* wo = (const float*)d_in[6];
    const float* R = (const float*)d_in[7];
    const float* cbias = (const float*)d_in[8];
    const float* gsc = (const float*)d_in[9];
    const float* gbi = (const float*)d_in[10];
    float* out = (float*)d_out;

    char* ws = (char*)d_ws;
    float* xc = (float*)ws;                           // 33,554,432 B
    float* gates = (float*)(ws + 33554432ull);        // 134,217,728 B
    float* yb = (float*)(ws + 167772160ull);          // 33,554,432 B
    int* Wq = (int*)(ws + 201326592ull);              // 1,048,576 B
    float* scales = (float*)(ws + 202375168ull);      // 16,384 B

    k_prep<<<1024, 256, 0, stream>>>(R, Wq, scales);
    k_conv<<<BB * SS, 256, 0, stream>>>(x, cw, cb, xc);
    k_gemm<<<dim3(128, 8, 8), 256, 0, stream>>>(x, xc, wi, wf, wz, wo, gates);
    k_scan<<<16, 1024, 0, stream>>>(gates, Wq, scales, cbias, yb);
    k_ln<<<BB * SS * NH, 256, 0, stream>>>(yb, gsc, gbi, out);
}